// Round 7
// baseline (959.371 us; speedup 1.0000x reference)
//
#include <hip/hip_runtime.h>
#include <stdint.h>

#define B_SZ   8192
#define IN_DIM 512
#define HID    256
#define PROJ   128

typedef __attribute__((ext_vector_type(8))) short bf16x8;
typedef __attribute__((ext_vector_type(4))) float f32x4;

#define GLDS16(gp, lp) __builtin_amdgcn_global_load_lds( \
    (const __attribute__((address_space(1))) void*)(gp), \
    (__attribute__((address_space(3))) void*)(lp), 16, 0, 0)

__device__ __forceinline__ unsigned short f2bf(float f) {
    union { float f; uint32_t u; } c; c.f = f;
    uint32_t u = c.u;
    uint32_t r = (u + 0x7fffu + ((u >> 16) & 1u)) >> 16;   // RNE
    return (unsigned short)r;
}

__device__ __forceinline__ float bfhi(uint32_t v) {   // high bf16 of dword
    union { uint32_t u; float f; } c; c.u = v & 0xffff0000u; return c.f;
}
__device__ __forceinline__ float bflo(uint32_t v) {   // low bf16 of dword
    union { uint32_t u; float f; } c; c.u = v << 16; return c.f;
}

// ------- K0: convert W2 to bf16 (blocks 0..2047) + transpose x to bf16 ----
__global__ __launch_bounds__(256) void k0_prep(
        const float4* __restrict__ W2, ushort4* __restrict__ W2b,
        const float* __restrict__ x, unsigned short* __restrict__ xTb) {
    __shared__ float tile[64][65];
    const int bid = blockIdx.x;
    if (bid < 2048) {
        const int nW2 = (PROJ * IN_DIM * HID) / 4;   // 4,194,304 float4s
        const int stride = 2048 * 256;
        for (int i = bid * 256 + threadIdx.x; i < nW2; i += stride) {
            float4 v = W2[i];
            ushort4 o;
            o.x = f2bf(v.x); o.y = f2bf(v.y); o.z = f2bf(v.z); o.w = f2bf(v.w);
            W2b[i] = o;
        }
    } else {
        const int tb = bid - 2048;
        const int bi = tb & 7, bb = tb >> 3;
        const int i0 = bi * 64, b0 = bb * 64;
        const int t = threadIdx.x;
        const int c = t & 63, r4 = t >> 6;
        #pragma unroll
        for (int rr = 0; rr < 64; rr += 4)
            tile[rr + r4][c] = x[(size_t)(b0 + rr + r4) * IN_DIM + i0 + c];
        __syncthreads();
        #pragma unroll
        for (int rr = 0; rr < 64; rr += 4)
            xTb[(size_t)(i0 + rr + r4) * B_SZ + b0 + c] = f2bf(tile[c][rr + r4]);
    }
}

// ---------------- K1: h = relu(ft @ W1^T + b1), bf16 out -----------------
// converts ft/W1 to bf16 inline (RNE) — no staging pass needed.
__device__ __forceinline__ bf16x8 ld_cvt8(const float* __restrict__ s) {
    float4 a = *(const float4*)s;
    float4 b = *(const float4*)(s + 4);
    bf16x8 r;
    r[0] = (short)f2bf(a.x); r[1] = (short)f2bf(a.y);
    r[2] = (short)f2bf(a.z); r[3] = (short)f2bf(a.w);
    r[4] = (short)f2bf(b.x); r[5] = (short)f2bf(b.y);
    r[6] = (short)f2bf(b.z); r[7] = (short)f2bf(b.w);
    return r;
}

__global__ __launch_bounds__(256) void k1_hidden(
        const float* __restrict__ ft,
        const float* __restrict__ W1,
        const float* __restrict__ b1,
        unsigned short* __restrict__ hb) {
    const int lane = threadIdx.x & 63;
    const int wv   = threadIdx.x >> 6;
    const int l15  = lane & 15, q = lane >> 4;
    const int b0 = blockIdx.x * 64;
    const int n0 = wv * 64;

    f32x4 acc[4][4];
    const f32x4 z4 = {0.f, 0.f, 0.f, 0.f};
    #pragma unroll
    for (int mt = 0; mt < 4; ++mt)
        #pragma unroll
        for (int nt = 0; nt < 4; ++nt) acc[mt][nt] = z4;

    for (int kq = 0; kq < 16; ++kq) {
        const int koff = kq * 32 + q * 8;
        bf16x8 a[4], bb[4];
        #pragma unroll
        for (int mt = 0; mt < 4; ++mt)
            a[mt] = ld_cvt8(ft + (size_t)(b0 + mt*16 + l15) * IN_DIM + koff);
        #pragma unroll
        for (int nt = 0; nt < 4; ++nt)
            bb[nt] = ld_cvt8(W1 + (size_t)(n0 + nt*16 + l15) * IN_DIM + koff);
        #pragma unroll
        for (int mt = 0; mt < 4; ++mt)
            #pragma unroll
            for (int nt = 0; nt < 4; ++nt)
                acc[mt][nt] = __builtin_amdgcn_mfma_f32_16x16x32_bf16(
                    a[mt], bb[nt], acc[mt][nt], 0, 0, 0);
    }
    #pragma unroll
    for (int nt = 0; nt < 4; ++nt) {
        float bias = b1[n0 + nt*16 + l15];
        #pragma unroll
        for (int mt = 0; mt < 4; ++mt)
            #pragma unroll
            for (int r = 0; r < 4; ++r) {
                float v = acc[mt][nt][r] + bias;
                v = fmaxf(v, 0.f);
                hb[(size_t)(b0 + mt*16 + q*4 + r) * HID + n0 + nt*16 + l15] = f2bf(v);
            }
    }
}

// ---------------- K3: out[b,p] = sum_i x*(sum_k h*W2 + b2) ---------------
// Block = ONE wave (64 threads), NO barriers. Wave owns private 2x8KB LDS
// double buffer; W2 tile (1p x 32i x 128k) staged via global_load_lds;
// completion via wave-local vmcnt only (AITER-style self-paced pipeline).
// m_w = 128 b-rows/wave: afr 128 VGPRs, 8 independent MFMA chains (hides
// dep latency), LDS-bytes/FLOP halved vs R6. Grid = sup*128 + p: same-XCD
// blocks share p%8 (W2 slice 4MB = L2); same-CU waves likely same p (L1).
// x as bf16 (2-instr unpack); b2 folded as (D+b2v)*x at kh=0.
__global__ __launch_bounds__(64, 2) void k3_main(
        const unsigned short* __restrict__ W2b,
        const unsigned short* __restrict__ hb,
        const unsigned short* __restrict__ xTb,
        const float* __restrict__ b2,
        float* __restrict__ out) {
    __shared__ unsigned short lbs[2][4096];   // 2 x 8 KB, private to this wave
    const int lane = threadIdx.x;
    const int l15  = lane & 15, q = lane >> 4;
    const int p    = blockIdx.x & 127;
    const int sup  = blockIdx.x >> 7;         // 0..63
    const int b0   = sup * 128;
    const f32x4 z4 = {0.f, 0.f, 0.f, 0.f};

    // glds geometry: 8 instrs j; instr j covers tile rows 4j..4j+3;
    // lane l -> row 4j+(l>>4), physical chunk l&15, source chunk (l&15)^(row&7)
    const int rowsub = lane >> 4;
    const int cbase  = l15 ^ rowsub;

    f32x4 oacc[8];
    #pragma unroll
    for (int mt = 0; mt < 8; ++mt) oacc[mt] = z4;

    bf16x8 afr[8][4];

    const unsigned short* Wp = W2b + (size_t)p * 512 * HID;   // this p's 256 KB

    // ---- prologue: stage tile 0 (kh=0, i0=0) ----
    #pragma unroll
    for (int j = 0; j < 8; ++j) {
        const int row = j * 4 + rowsub;
        const int c   = cbase ^ (4 * (j & 1));
        GLDS16(Wp + (size_t)row * HID + c * 8, &lbs[0][j * 512]);
    }

    #pragma unroll 1
    for (int t = 0; t < 32; ++t) {
        const int kh = t >> 4;
        const int i0 = (t & 15) * 32;

        if (t < 31) {          // prefetch tile t+1 (wave-local, no barrier)
            const int tn = t + 1;
            const int kh_n = tn >> 4, i0_n = (tn & 15) * 32;
            unsigned short* Ld = lbs[tn & 1];
            #pragma unroll
            for (int j = 0; j < 8; ++j) {
                const int row = j * 4 + rowsub;
                const int c   = cbase ^ (4 * (j & 1));
                GLDS16(Wp + ((size_t)(i0_n + row)) * HID + kh_n * 128 + c * 8,
                       &Ld[j * 512]);
            }
        }

        if ((t & 15) == 0) {   // load h fragments for this K-half (2x per kernel)
            #pragma unroll
            for (int mt = 0; mt < 8; ++mt) {
                const unsigned short* hrow =
                    hb + (size_t)(b0 + mt*16 + l15) * HID + kh * 128 + q * 8;
                #pragma unroll
                for (int kq = 0; kq < 4; ++kq)
                    afr[mt][kq] = *(const bf16x8*)(hrow + kq * 32);
            }
        }

        const unsigned short* Lb = lbs[t & 1];

        #pragma unroll
        for (int sub = 0; sub < 2; ++sub) {
            const int irow = i0 + sub * 16 + l15;
            // x loads (bf16, 4 b-values = 8 B per mt)
            uint2 xv[8];
            const unsigned short* xp = xTb + (size_t)irow * B_SZ + b0 + q * 4;
            #pragma unroll
            for (int mt = 0; mt < 8; ++mt)
                xv[mt] = *(const uint2*)(xp + mt * 16);

            bf16x8 bfr[4];
            #pragma unroll
            for (int kq = 0; kq < 4; ++kq) {
                const int cpos = (kq * 4 + q) ^ (l15 & 7);
                bfr[kq] = *(const bf16x8*)(Lb + (size_t)(sub*16 + l15) * 128 + cpos * 8);
            }

            f32x4 D[8];
            #pragma unroll
            for (int mt = 0; mt < 8; ++mt)
                D[mt] = __builtin_amdgcn_mfma_f32_16x16x32_bf16(afr[mt][0], bfr[0], z4, 0, 0, 0);
            #pragma unroll
            for (int kq = 1; kq < 4; ++kq)
                #pragma unroll
                for (int mt = 0; mt < 8; ++mt)
                    D[mt] = __builtin_amdgcn_mfma_f32_16x16x32_bf16(afr[mt][kq], bfr[kq], D[mt], 0, 0, 0);

            if (kh == 0) {
                const float b2v = b2[p * 512 + irow];
                #pragma unroll
                for (int mt = 0; mt < 8; ++mt) {
                    oacc[mt][0] = fmaf(D[mt][0] + b2v, bflo(xv[mt].x), oacc[mt][0]);
                    oacc[mt][1] = fmaf(D[mt][1] + b2v, bfhi(xv[mt].x), oacc[mt][1]);
                    oacc[mt][2] = fmaf(D[mt][2] + b2v, bflo(xv[mt].y), oacc[mt][2]);
                    oacc[mt][3] = fmaf(D[mt][3] + b2v, bfhi(xv[mt].y), oacc[mt][3]);
                }
            } else {
                #pragma unroll
                for (int mt = 0; mt < 8; ++mt) {
                    oacc[mt][0] = fmaf(D[mt][0], bflo(xv[mt].x), oacc[mt][0]);
                    oacc[mt][1] = fmaf(D[mt][1], bfhi(xv[mt].x), oacc[mt][1]);
                    oacc[mt][2] = fmaf(D[mt][2], bflo(xv[mt].y), oacc[mt][2]);
                    oacc[mt][3] = fmaf(D[mt][3], bfhi(xv[mt].y), oacc[mt][3]);
                }
            }
        }
    }

    // ---- epilogue: reduce over the 16 i-lanes, lane 0 of each q stores ----
    #pragma unroll
    for (int mt = 0; mt < 8; ++mt)
        #pragma unroll
        for (int r = 0; r < 4; ++r) {
            float v = oacc[mt][r];
            v += __shfl_xor(v, 1, 16);
            v += __shfl_xor(v, 2, 16);
            v += __shfl_xor(v, 4, 16);
            v += __shfl_xor(v, 8, 16);
            if (l15 == 0)
                out[(size_t)(b0 + mt*16 + q*4 + r) * PROJ + p] = v;
        }
}

extern "C" void kernel_launch(void* const* d_in, const int* in_sizes, int n_in,
                              void* d_out, int out_size, void* d_ws, size_t ws_size,
                              hipStream_t stream) {
    const float* ft = (const float*)d_in[0];
    const float* x  = (const float*)d_in[1];
    const float* W1 = (const float*)d_in[2];
    const float* b1 = (const float*)d_in[3];
    const float* W2 = (const float*)d_in[4];
    const float* b2 = (const float*)d_in[5];
    float* out = (float*)d_out;

    char* ws = (char*)d_ws;
    unsigned short* W2b = (unsigned short*)(ws);             // 33,554,432 B
    unsigned short* hb  = (unsigned short*)(ws + 33554432);  //  4,194,304 B
    unsigned short* xTb = (unsigned short*)(ws + 37748736);  //  8,388,608 B
                                                             // total ~46 MB

    hipLaunchKernelGGL(k0_prep, dim3(3072), dim3(256), 0, stream,
        (const float4*)W2, (ushort4*)W2b, x, xTb);
    hipLaunchKernelGGL(k1_hidden, dim3(128), dim3(256), 0, stream, ft, W1, b1, hb);
    hipLaunchKernelGGL(k3_main, dim3(8192), dim3(64), 0, stream, W2b, hb, xTb, b2, out);
}

// Round 8
// 489.599 us; speedup vs baseline: 1.9595x; 1.9595x over previous
//
#include <hip/hip_runtime.h>
#include <stdint.h>

#define B_SZ   8192
#define IN_DIM 512
#define HID    256
#define PROJ   128

typedef __attribute__((ext_vector_type(8))) short bf16x8;
typedef __attribute__((ext_vector_type(4))) float f32x4;

#define GLDS16(gp, lp) __builtin_amdgcn_global_load_lds( \
    (const __attribute__((address_space(1))) void*)(gp), \
    (__attribute__((address_space(3))) void*)(lp), 16, 0, 0)

__device__ __forceinline__ unsigned short f2bf(float f) {
    union { float f; uint32_t u; } c; c.f = f;
    uint32_t u = c.u;
    uint32_t r = (u + 0x7fffu + ((u >> 16) & 1u)) >> 16;   // RNE
    return (unsigned short)r;
}
__device__ __forceinline__ float bfhi(uint32_t v) {
    union { uint32_t u; float f; } c; c.u = v & 0xffff0000u; return c.f;
}
__device__ __forceinline__ float bflo(uint32_t v) {
    union { uint32_t u; float f; } c; c.u = v << 16; return c.f;
}

// ------- K0: convert W2 to bf16 (blocks 0..2047) + transpose x to bf16 ----
__global__ __launch_bounds__(256) void k0_prep(
        const float4* __restrict__ W2, ushort4* __restrict__ W2b,
        const float* __restrict__ x, unsigned short* __restrict__ xTb) {
    __shared__ float tile[64][65];
    const int bid = blockIdx.x;
    if (bid < 2048) {
        const int nW2 = (PROJ * IN_DIM * HID) / 4;
        const int stride = 2048 * 256;
        for (int i = bid * 256 + threadIdx.x; i < nW2; i += stride) {
            float4 v = W2[i];
            ushort4 o;
            o.x = f2bf(v.x); o.y = f2bf(v.y); o.z = f2bf(v.z); o.w = f2bf(v.w);
            W2b[i] = o;
        }
    } else {
        const int tb = bid - 2048;
        const int bi = tb & 7, bb = tb >> 3;
        const int i0 = bi * 64, b0 = bb * 64;
        const int t = threadIdx.x;
        const int c = t & 63, r4 = t >> 6;
        #pragma unroll
        for (int rr = 0; rr < 64; rr += 4)
            tile[rr + r4][c] = x[(size_t)(b0 + rr + r4) * IN_DIM + i0 + c];
        __syncthreads();
        #pragma unroll
        for (int rr = 0; rr < 64; rr += 4)
            xTb[(size_t)(i0 + rr + r4) * B_SZ + b0 + c] = f2bf(tile[c][rr + r4]);
    }
}

// ---------------- K1: h = relu(ft @ W1^T + b1), bf16 out -----------------
__device__ __forceinline__ bf16x8 ld_cvt8(const float* __restrict__ s) {
    float4 a = *(const float4*)s;
    float4 b = *(const float4*)(s + 4);
    bf16x8 r;
    r[0] = (short)f2bf(a.x); r[1] = (short)f2bf(a.y);
    r[2] = (short)f2bf(a.z); r[3] = (short)f2bf(a.w);
    r[4] = (short)f2bf(b.x); r[5] = (short)f2bf(b.y);
    r[6] = (short)f2bf(b.z); r[7] = (short)f2bf(b.w);
    return r;
}

__global__ __launch_bounds__(256) void k1_hidden(
        const float* __restrict__ ft,
        const float* __restrict__ W1,
        const float* __restrict__ b1,
        unsigned short* __restrict__ hb) {
    const int lane = threadIdx.x & 63;
    const int wv   = threadIdx.x >> 6;
    const int l15  = lane & 15, q = lane >> 4;
    const int b0 = blockIdx.x * 64;
    const int n0 = wv * 64;

    f32x4 acc[4][4];
    const f32x4 z4 = {0.f, 0.f, 0.f, 0.f};
    #pragma unroll
    for (int mt = 0; mt < 4; ++mt)
        #pragma unroll
        for (int nt = 0; nt < 4; ++nt) acc[mt][nt] = z4;

    for (int kq = 0; kq < 16; ++kq) {
        const int koff = kq * 32 + q * 8;
        bf16x8 a[4], bb[4];
        #pragma unroll
        for (int mt = 0; mt < 4; ++mt)
            a[mt] = ld_cvt8(ft + (size_t)(b0 + mt*16 + l15) * IN_DIM + koff);
        #pragma unroll
        for (int nt = 0; nt < 4; ++nt)
            bb[nt] = ld_cvt8(W1 + (size_t)(n0 + nt*16 + l15) * IN_DIM + koff);
        #pragma unroll
        for (int mt = 0; mt < 4; ++mt)
            #pragma unroll
            for (int nt = 0; nt < 4; ++nt)
                acc[mt][nt] = __builtin_amdgcn_mfma_f32_16x16x32_bf16(
                    a[mt], bb[nt], acc[mt][nt], 0, 0, 0);
    }
    #pragma unroll
    for (int nt = 0; nt < 4; ++nt) {
        float bias = b1[n0 + nt*16 + l15];
        #pragma unroll
        for (int mt = 0; mt < 4; ++mt)
            #pragma unroll
            for (int r = 0; r < 4; ++r) {
                float v = acc[mt][nt][r] + bias;
                v = fmaxf(v, 0.f);
                hb[(size_t)(b0 + mt*16 + q*4 + r) * HID + n0 + nt*16 + l15] = f2bf(v);
            }
    }
}

// ---------------- K3: out[b,p] = sum_i x*(sum_k h*W2 + b2) ---------------
// Block = 4 waves x 32 b-rows = 128 rows, one p-pair. W2 tile (2p x 32i x
// 128k = 16 KB) double-buffered in LDS via global_load_lds w16, XOR-swizzled
// (chunk c of row r at c^(r&7)) -> 2-way (free) ds_read_b128. Single
// barrier per step. mt=2 shrinks per-wave regs to ~110 so (256,4) fits
// WITHOUT spilling (R5's mt=4 did not) -> 4 waves/SIMD of independent
// phase to interleave the per-step latency chain. x bf16, b2 folded at kh=0.
__global__ __launch_bounds__(256, 4) void k3_main(
        const unsigned short* __restrict__ W2b,
        const unsigned short* __restrict__ hb,
        const unsigned short* __restrict__ xTb,
        const float* __restrict__ b2,
        float* __restrict__ out) {
    __shared__ unsigned short lbs[2][64 * 128];   // 2 x 16 KB
    const int tid  = threadIdx.x;
    const int lane = tid & 63;
    const int wv   = tid >> 6;
    const int l15  = lane & 15, q = lane >> 4;
    const int pgrp = blockIdx.x & 63;             // stride-64 => same XCD per p-pair
    const int bsup = blockIdx.x >> 6;             // 0..63
    const int p0   = pgrp * 2;
    const int b0w  = bsup * 128 + wv * 32;
    const f32x4 z4 = {0.f, 0.f, 0.f, 0.f};

    const int grow_sub = lane >> 4;               // row within 4-row group
    const int cbase    = (lane & 15) ^ grow_sub;  // writer swizzle base

    const int qx   = q ^ (l15 & 3);               // reader swizzle
    const int kbit = (l15 >> 2) & 1;

    float oacc[2][2][4];
    #pragma unroll
    for (int pp = 0; pp < 2; ++pp)
        #pragma unroll
        for (int mt = 0; mt < 2; ++mt)
            #pragma unroll
            for (int r = 0; r < 4; ++r) oacc[pp][mt][r] = 0.f;

    bf16x8 afr[2][4];

    // ---- prologue: issue tile 0 ----
    {
        #pragma unroll
        for (int jj = 0; jj < 4; ++jj) {
            const int j   = wv * 4 + jj;
            const int row = j * 4 + grow_sub;
            const int p   = row >> 5, ir = row & 31;
            const int c   = cbase ^ (4 * (jj & 1));
            const unsigned short* g = W2b
                + ((size_t)(p0 + p) * IN_DIM + ir) * HID + c * 8;
            GLDS16(g, &lbs[0][j * 512]);
        }
    }

    #pragma unroll 1
    for (int t = 0; t < 32; ++t) {
        __syncthreads();   // drains tile-t glds; all waves done with buf[(t-1)&1]

        if (t < 31) {      // prefetch t+1 into the buffer just released
            const int tn = t + 1;
            const int kh = tn >> 4, i0 = (tn & 15) * 32;
            unsigned short* Ld = lbs[tn & 1];
            #pragma unroll
            for (int jj = 0; jj < 4; ++jj) {
                const int j   = wv * 4 + jj;
                const int row = j * 4 + grow_sub;
                const int p   = row >> 5, ir = row & 31;
                const int c   = cbase ^ (4 * (jj & 1));
                const unsigned short* g = W2b
                    + ((size_t)(p0 + p) * IN_DIM + i0 + ir) * HID + kh * 128 + c * 8;
                GLDS16(g, &Ld[j * 512]);
            }
        }

        const int kh = t >> 4;
        if ((t & 15) == 0) {   // load h fragments for this K-half
            #pragma unroll
            for (int mt = 0; mt < 2; ++mt) {
                const unsigned short* hrow =
                    hb + (size_t)(b0w + mt*16 + l15) * HID + kh * 128 + q * 8;
                #pragma unroll
                for (int kq = 0; kq < 4; ++kq)
                    afr[mt][kq] = *(const bf16x8*)(hrow + kq * 32);
            }
        }

        const unsigned short* Lb = lbs[t & 1];
        const int i0 = (t & 15) * 32;

        #pragma unroll
        for (int sub = 0; sub < 2; ++sub) {
            const int irow = i0 + sub * 16 + l15;
            uint2 xv[2];
            const unsigned short* xp = xTb + (size_t)irow * B_SZ + b0w + q * 4;
            #pragma unroll
            for (int mt = 0; mt < 2; ++mt)
                xv[mt] = *(const uint2*)(xp + mt * 16);

            const float b2v = (kh == 0) ? b2[p0 * 512 + irow] : 0.f;        // pp=0
            const float b2w = (kh == 0) ? b2[(p0 + 1) * 512 + irow] : 0.f;  // pp=1

            #pragma unroll
            for (int pp = 0; pp < 2; ++pp) {
                const unsigned short* Bp = Lb + (pp*32 + sub*16 + l15) * 128;
                bf16x8 bfr[4];
                #pragma unroll
                for (int kq = 0; kq < 4; ++kq) {
                    const int cpos = qx + 4 * (kq ^ kbit);
                    bfr[kq] = *(const bf16x8*)(Bp + cpos * 8);
                }

                f32x4 D[2];
                #pragma unroll
                for (int mt = 0; mt < 2; ++mt)
                    D[mt] = __builtin_amdgcn_mfma_f32_16x16x32_bf16(afr[mt][0], bfr[0], z4, 0, 0, 0);
                #pragma unroll
                for (int kq = 1; kq < 4; ++kq)
                    #pragma unroll
                    for (int mt = 0; mt < 2; ++mt)
                        D[mt] = __builtin_amdgcn_mfma_f32_16x16x32_bf16(afr[mt][kq], bfr[kq], D[mt], 0, 0, 0);

                const float bb = pp ? b2w : b2v;
                #pragma unroll
                for (int mt = 0; mt < 2; ++mt) {
                    oacc[pp][mt][0] = fmaf(D[mt][0] + bb, bflo(xv[mt].x), oacc[pp][mt][0]);
                    oacc[pp][mt][1] = fmaf(D[mt][1] + bb, bfhi(xv[mt].x), oacc[pp][mt][1]);
                    oacc[pp][mt][2] = fmaf(D[mt][2] + bb, bflo(xv[mt].y), oacc[pp][mt][2]);
                    oacc[pp][mt][3] = fmaf(D[mt][3] + bb, bfhi(xv[mt].y), oacc[pp][mt][3]);
                }
            }
        }
        // next iteration's top barrier covers buffer release + glds drain
    }

    // ---- epilogue: reduce over 16 i-lanes, store ----
    #pragma unroll
    for (int pp = 0; pp < 2; ++pp)
        #pragma unroll
        for (int mt = 0; mt < 2; ++mt)
            #pragma unroll
            for (int r = 0; r < 4; ++r) {
                float v = oacc[pp][mt][r];
                v += __shfl_xor(v, 1, 16);
                v += __shfl_xor(v, 2, 16);
                v += __shfl_xor(v, 4, 16);
                v += __shfl_xor(v, 8, 16);
                if (l15 == 0)
                    out[(size_t)(b0w + mt*16 + q*4 + r) * PROJ + p0 + pp] = v;
            }
}

extern "C" void kernel_launch(void* const* d_in, const int* in_sizes, int n_in,
                              void* d_out, int out_size, void* d_ws, size_t ws_size,
                              hipStream_t stream) {
    const float* ft = (const float*)d_in[0];
    const float* x  = (const float*)d_in[1];
    const float* W1 = (const float*)d_in[2];
    const float* b1 = (const float*)d_in[3];
    const float* W2 = (const float*)d_in[4];
    const float* b2 = (const float*)d_in[5];
    float* out = (float*)d_out;

    char* ws = (char*)d_ws;
    unsigned short* W2b = (unsigned short*)(ws);             // 33,554,432 B
    unsigned short* hb  = (unsigned short*)(ws + 33554432);  //  4,194,304 B
    unsigned short* xTb = (unsigned short*)(ws + 37748736);  //  8,388,608 B

    hipLaunchKernelGGL(k0_prep, dim3(3072), dim3(256), 0, stream,
        (const float4*)W2, (ushort4*)W2b, x, xTb);
    hipLaunchKernelGGL(k1_hidden, dim3(128), dim3(256), 0, stream, ft, W1, b1, hb);
    hipLaunchKernelGGL(k3_main, dim3(4096), dim3(256), 0, stream, W2b, hb, xTb, b2, out);
}